// Round 9
// baseline (413.911 us; speedup 1.0000x reference)
//
#include <hip/hip_runtime.h>
#include <stdint.h>

// ---------------------------------------------------------------------------
// Causal self-attention, MI355X bf16-MFMA, round 9.
//   1. cast_all: x -> bf16, wq|wk|wv|wo -> bf16 (wq pre-scaled by 1/8*log2e)
//   2. gemm_qkv (BK=64, XOR-swizzled LDS): Q,K -> QKV; V written directly to
//      Vt[bh][d][2048] with per-64-key permutation sigma (fused transpose)
//   3. attn: single 128q tile/block, 1024 blocks (ALL resident: 4 blocks/CU
//      via 32 KB LDS + VGPR<=64), balanced qt permutation, simple 2-barrier
//      loop (cross-block overlap hides staging latency), diagonal t-skip
//   4. gemm_out: out = O @ wo.T (fp32)
// ---------------------------------------------------------------------------

typedef __attribute__((ext_vector_type(8))) short bf16x8;
typedef __attribute__((ext_vector_type(4))) float f32x4;
typedef unsigned short us;

#define LOG2E 1.4426950408889634f

#define GL2LDS16(g, l)                                                          \
  __builtin_amdgcn_global_load_lds(                                             \
      (const __attribute__((address_space(1))) unsigned int*)(g),               \
      (__attribute__((address_space(3))) unsigned int*)(l), 16, 0, 0)

__device__ inline us f2bf(float f) {
  union { float f; unsigned int u; } v; v.f = f;
  unsigned int u = v.u;
  u += 0x7FFFu + ((u >> 16) & 1u);
  return (us)(u >> 16);
}

// ---------------------------- fused casts ----------------------------------
__global__ void cast_all(const float* __restrict__ x,
                         const float* __restrict__ w0, const float* __restrict__ w1,
                         const float* __restrict__ w2, const float* __restrict__ w3,
                         us* __restrict__ xb, us* __restrict__ wbuf) {
  int i = (blockIdx.x * blockDim.x + threadIdx.x) * 8;
  const float* src;
  us* dst;
  float sc = 1.0f;
  if (i < (8 << 20)) {
    src = x + i; dst = xb + i;
  } else {
    int j = i - (8 << 20);
    int seg = j >> 20;
    int off = j & ((1 << 20) - 1);
    const float* w = (seg == 0) ? w0 : (seg == 1) ? w1 : (seg == 2) ? w2 : w3;
    if (seg == 0) sc = 0.125f * LOG2E;
    src = w + off; dst = wbuf + j;
  }
  float4 a = *reinterpret_cast<const float4*>(src);
  float4 b = *reinterpret_cast<const float4*>(src + 4);
  union { us u[8]; uint4 v; } o;
  o.u[0] = f2bf(a.x * sc); o.u[1] = f2bf(a.y * sc);
  o.u[2] = f2bf(a.z * sc); o.u[3] = f2bf(a.w * sc);
  o.u[4] = f2bf(b.x * sc); o.u[5] = f2bf(b.y * sc);
  o.u[6] = f2bf(b.z * sc); o.u[7] = f2bf(b.w * sc);
  *reinterpret_cast<uint4*>(dst) = o.v;
}

// -------------------- QKV GEMM (B^T), BK=64, fused V-transpose -------------
__global__ __launch_bounds__(256, 2) void gemm_qkv(
    const us* __restrict__ A, const us* __restrict__ Bw,
    us* __restrict__ QKV, us* __restrict__ Vt) {
  const int K = 1024, N = 3072;
  __shared__ __align__(16) us Al[128 * 64];
  __shared__ __align__(16) us Bl[128 * 64];
  const int tid = threadIdx.x;
  const int lane = tid & 63;
  const int w = tid >> 6;
  const int quad = lane >> 4;
  const int l16 = lane & 15;
  const int m0 = blockIdx.y * 128;
  const int n0 = blockIdx.x * 128;
  const int wm = w >> 1, wn = w & 1;
  const int srow_base = w * 8 + (lane >> 3);
  const int sunit = lane & 7;
  f32x4 acc[4][4] = {};

  for (int k0 = 0; k0 < K; k0 += 64) {
    __syncthreads();
#pragma unroll
    for (int it = 0; it < 4; ++it) {
      int row = it * 32 + srow_base;
      int gu = sunit ^ (row & 7);
      int base = __builtin_amdgcn_readfirstlane((it * 256 + w * 64) * 8);
      GL2LDS16(A + (size_t)(m0 + row) * K + k0 + gu * 8, &Al[base]);
      GL2LDS16(Bw + (size_t)(n0 + row) * K + k0 + gu * 8, &Bl[base]);
    }
    __syncthreads();
#pragma unroll
    for (int kk = 0; kk < 2; ++kk) {
      bf16x8 af[4], bfr[4];
#pragma unroll
      for (int mi = 0; mi < 4; ++mi) {
        int row = wm * 64 + mi * 16 + l16;
        af[mi] = *reinterpret_cast<const bf16x8*>(
            &Al[row * 64 + (((kk * 4 + quad) ^ (row & 7)) * 8)]);
      }
#pragma unroll
      for (int ni = 0; ni < 4; ++ni) {
        int row = wn * 64 + ni * 16 + l16;
        bfr[ni] = *reinterpret_cast<const bf16x8*>(
            &Bl[row * 64 + (((kk * 4 + quad) ^ (row & 7)) * 8)]);
      }
#pragma unroll
      for (int mi = 0; mi < 4; ++mi)
#pragma unroll
        for (int ni = 0; ni < 4; ++ni)
          acc[mi][ni] = __builtin_amdgcn_mfma_f32_16x16x32_bf16(af[mi], bfr[ni], acc[mi][ni], 0, 0, 0);
    }
  }

  if (n0 < 2048) {
#pragma unroll
    for (int mi = 0; mi < 4; ++mi)
#pragma unroll
      for (int ni = 0; ni < 4; ++ni)
#pragma unroll
        for (int r = 0; r < 4; ++r) {
          int row = m0 + wm * 64 + mi * 16 + quad * 4 + r;
          int col = n0 + wn * 64 + ni * 16 + l16;
          QKV[(size_t)row * N + col] = f2bf(acc[mi][ni][r]);
        }
  } else {
    const int b = m0 >> 11;
    const int kt = ((m0 & 2047) >> 6) + wm;
#pragma unroll
    for (int mi = 0; mi < 4; ++mi)
#pragma unroll
      for (int ni = 0; ni < 4; ++ni)
#pragma unroll
        for (int r = 0; r < 4; ++r) {
          int col = n0 + wn * 64 + ni * 16 + l16;
          int h = (col - 2048) >> 6;
          int d = col & 63;
          int sj = (quad * 4 + r) * 4 + mi;
          Vt[((size_t)((b * 16 + h) * 64 + d)) * 2048 + kt * 64 + sj] = f2bf(acc[mi][ni][r]);
        }
  }
}

// ------------------------- out-proj GEMM (B^T), BK=64 ----------------------
__global__ __launch_bounds__(256, 2) void gemm_out(
    const us* __restrict__ A, const us* __restrict__ Bw,
    float* __restrict__ Cv, int M, int N, int K) {
  __shared__ __align__(16) us Al[128 * 64];
  __shared__ __align__(16) us Bl[128 * 64];
  const int tid = threadIdx.x;
  const int lane = tid & 63;
  const int w = tid >> 6;
  const int quad = lane >> 4;
  const int l16 = lane & 15;
  const int m0 = blockIdx.y * 128;
  const int n0 = blockIdx.x * 128;
  const int wm = w >> 1, wn = w & 1;
  const int srow_base = w * 8 + (lane >> 3);
  const int sunit = lane & 7;
  f32x4 acc[4][4] = {};

  for (int k0 = 0; k0 < K; k0 += 64) {
    __syncthreads();
#pragma unroll
    for (int it = 0; it < 4; ++it) {
      int row = it * 32 + srow_base;
      int gu = sunit ^ (row & 7);
      int base = __builtin_amdgcn_readfirstlane((it * 256 + w * 64) * 8);
      GL2LDS16(A + (size_t)(m0 + row) * K + k0 + gu * 8, &Al[base]);
      GL2LDS16(Bw + (size_t)(n0 + row) * K + k0 + gu * 8, &Bl[base]);
    }
    __syncthreads();
#pragma unroll
    for (int kk = 0; kk < 2; ++kk) {
      bf16x8 af[4], bfr[4];
#pragma unroll
      for (int mi = 0; mi < 4; ++mi) {
        int row = wm * 64 + mi * 16 + l16;
        af[mi] = *reinterpret_cast<const bf16x8*>(
            &Al[row * 64 + (((kk * 4 + quad) ^ (row & 7)) * 8)]);
      }
#pragma unroll
      for (int ni = 0; ni < 4; ++ni) {
        int row = wn * 64 + ni * 16 + l16;
        bfr[ni] = *reinterpret_cast<const bf16x8*>(
            &Bl[row * 64 + (((kk * 4 + quad) ^ (row & 7)) * 8)]);
      }
#pragma unroll
      for (int mi = 0; mi < 4; ++mi)
#pragma unroll
        for (int ni = 0; ni < 4; ++ni)
          acc[mi][ni] = __builtin_amdgcn_mfma_f32_16x16x32_bf16(af[mi], bfr[ni], acc[mi][ni], 0, 0, 0);
    }
  }

#pragma unroll
  for (int mi = 0; mi < 4; ++mi)
#pragma unroll
    for (int ni = 0; ni < 4; ++ni)
#pragma unroll
      for (int r = 0; r < 4; ++r) {
        int row = m0 + wm * 64 + mi * 16 + quad * 4 + r;
        int col = n0 + wn * 64 + ni * 16 + l16;
        Cv[(size_t)row * N + col] = acc[mi][ni][r];
      }
}

// ---------------------------- flash attention ------------------------------
// One 128q tile per block; 1024 blocks = 4 blocks/CU ALL resident.
// qt permutation: stride-4x64 bid samples sum to 30 -> balanced per-CU load
// regardless of round-robin dispatch; heavy tiles dispatched first.
// Simple 2-barrier staging loop; latency hidden by 4 independent blocks/CU.
__global__ __launch_bounds__(512, 8) void attn(
    const us* __restrict__ QKV, const us* __restrict__ Vt,
    us* __restrict__ O) {
  __shared__ __align__(16) us Kl[64 * 64];
  __shared__ __align__(16) us Vl[64 * 64];
  __shared__ __align__(16) us Pl[8][16 * 64];
  const int bid = blockIdx.x;
  const int g = bid >> 6;
  const int qt = (g < 4) ? (15 - g) : (g < 8) ? (g - 4) : (g < 12) ? (19 - g) : (g - 8);
  const int bh = bid & 63;
  const int b = bh >> 4, h = bh & 15;
  const int q0 = qt * 128;
  const int tid = threadIdx.x, lane = tid & 63, w = tid >> 6;   // w in [0,8)
  const int quad = lane >> 4, l16 = lane & 15;
  const size_t rowbase = (size_t)b * 2048;
  const int qcol = h * 64;
  const int kcol = 1024 + h * 64;
  const int qrow = q0 + w * 16;            // this wave's strip
  const int nT = 2 * qt + 2;

  const bf16x8 ones = {(short)0x3F80, (short)0x3F80, (short)0x3F80, (short)0x3F80,
                       (short)0x3F80, (short)0x3F80, (short)0x3F80, (short)0x3F80};

  bf16x8 qf[2];
#pragma unroll
  for (int dc = 0; dc < 2; ++dc)
    qf[dc] = *reinterpret_cast<const bf16x8*>(
        &QKV[(rowbase + qrow + l16) * 3072 + qcol + dc * 32 + quad * 8]);

  f32x4 oacc[4] = {};
  f32x4 lacc = {};

  const int rr = tid >> 3;                 // staged row 0..63
  const int gu = (tid & 7) ^ (rr & 7);     // source XOR swizzle
  const int sbase = __builtin_amdgcn_readfirstlane(w * 512);

  for (int kt = 0; kt < nT; ++kt) {
    __syncthreads();                       // everyone done reading prev tile
    GL2LDS16(QKV + (rowbase + kt * 64 + rr) * 3072 + kcol + gu * 8, &Kl[sbase]);
    GL2LDS16(Vt + ((size_t)((b * 16 + h) * 64 + rr)) * 2048 + kt * 64 + gu * 8,
             &Vl[sbase]);
    __syncthreads();                       // tile kt staged (vmcnt(0) drain)

    const int kdiff = qrow + 15 - kt * 64;
    if (kdiff < 0) continue;               // strip above diagonal
    const int tmax = (kdiff >= 48) ? 4 : ((kdiff >> 4) + 1);

    f32x4 s[4];
    float p[4][4];
#pragma unroll
    for (int t = 0; t < 4; ++t) {
      if (t < tmax) {
        s[t] = f32x4{0.f, 0.f, 0.f, 0.f};
        int krow = t * 16 + l16;
#pragma unroll
        for (int dc = 0; dc < 2; ++dc) {
          bf16x8 kf = *reinterpret_cast<const bf16x8*>(
              &Kl[krow * 64 + (((dc * 4 + quad) ^ (l16 & 7)) * 8)]);
          s[t] = __builtin_amdgcn_mfma_f32_16x16x32_bf16(qf[dc], kf, s[t], 0, 0, 0);
        }
      }
    }
    const bool do_mask = (kt * 64 + 63) > qrow;
#pragma unroll
    for (int t = 0; t < 4; ++t) {
      if (t < tmax) {
        if (do_mask) {
#pragma unroll
          for (int r = 0; r < 4; ++r) {
            float e = __builtin_amdgcn_exp2f(s[t][r]);
            int kg = kt * 64 + t * 16 + l16;
            int qgl = qrow + quad * 4 + r;
            p[t][r] = (kg <= qgl) ? e : 0.f;
          }
        } else {
#pragma unroll
          for (int r = 0; r < 4; ++r)
            p[t][r] = __builtin_amdgcn_exp2f(s[t][r]);
        }
      } else {
#pragma unroll
        for (int r = 0; r < 4; ++r) p[t][r] = 0.f;
      }
    }
#pragma unroll
    for (int r = 0; r < 4; ++r) {
      int prow = quad * 4 + r;
      uint2 val;
      val.x = __builtin_amdgcn_perm(__float_as_uint(p[1][r]), __float_as_uint(p[0][r]), 0x07060302u);
      val.y = __builtin_amdgcn_perm(__float_as_uint(p[3][r]), __float_as_uint(p[2][r]), 0x07060302u);
      char* dst = (char*)&Pl[w][0] + prow * 128 +
                  (((l16 >> 1) ^ (prow & 7)) * 16) + (l16 & 1) * 8;
      *reinterpret_cast<uint2*>(dst) = val;
    }
    asm volatile("s_waitcnt lgkmcnt(0)" ::: "memory");  // wave-local P RAW
#pragma unroll
    for (int kc = 0; kc < 2; ++kc) {
      bf16x8 pf = *reinterpret_cast<const bf16x8*>(
          (const char*)&Pl[w][0] + l16 * 128 + (((kc * 4 + quad) ^ (l16 & 7)) * 16));
      lacc = __builtin_amdgcn_mfma_f32_16x16x32_bf16(pf, ones, lacc, 0, 0, 0);
#pragma unroll
      for (int dt = 0; dt < 4; ++dt) {
        bf16x8 vf = *reinterpret_cast<const bf16x8*>(
            &Vl[(dt * 16 + l16) * 64 + (((kc * 4 + quad) ^ (l16 & 7)) * 8)]);
        oacc[dt] = __builtin_amdgcn_mfma_f32_16x16x32_bf16(pf, vf, oacc[dt], 0, 0, 0);
      }
    }
  }

#pragma unroll
  for (int dt = 0; dt < 4; ++dt)
#pragma unroll
    for (int r = 0; r < 4; ++r) {
      int row = qrow + quad * 4 + r;
      O[(rowbase + row) * 1024 + qcol + dt * 16 + l16] = f2bf(oacc[dt][r] / lacc[r]);
    }
}

// ------------------------------- launcher ----------------------------------
extern "C" void kernel_launch(void* const* d_in, const int* in_sizes, int n_in,
                              void* d_out, int out_size, void* d_ws, size_t ws_size,
                              hipStream_t stream) {
  const float* x = (const float*)d_in[0];
  const float* wq = (const float*)d_in[1];
  const float* wk = (const float*)d_in[2];
  const float* wv = (const float*)d_in[3];
  const float* wo = (const float*)d_in[4];

  const int BT = 8192, E = 1024;
  const size_t NX = (size_t)BT * E;
  const size_t NW = (size_t)E * E;

  us* xb = (us*)d_ws;                 // [8192][1024]; later reused as O
  us* wbuf = xb + NX;                 // wq|wk|wv|wo bf16
  us* QKV = wbuf + 4 * NW;            // [8192][3072] (V cols unused)
  us* VtB = QKV + (size_t)BT * 3 * E; // [64 bh][64 d][2048]
  us* Ob = xb;

  cast_all<<<(int)((NX + 4 * NW) / 8 / 256), 256, 0, stream>>>(x, wq, wk, wv, wo, xb, wbuf);

  gemm_qkv<<<dim3(24, 64), 256, 0, stream>>>(xb, wbuf, QKV, VtB);
  attn<<<1024, 512, 0, stream>>>(QKV, VtB, Ob);
  gemm_out<<<dim3(8, 64), 256, 0, stream>>>(Ob, wbuf + 3 * NW, (float*)d_out, BT, E, E);
}

// Round 10
// 237.523 us; speedup vs baseline: 1.7426x; 1.7426x over previous
//
#include <hip/hip_runtime.h>
#include <stdint.h>

// ---------------------------------------------------------------------------
// Causal self-attention, MI355X bf16-MFMA, round 10.
//   1. cast_all: x -> bf16, wq|wk|wv|wo -> bf16 (wq pre-scaled by 1/8*log2e)
//   2. gemm_qkv (BK=64, XOR-swizzled LDS): Q,K -> QKV; V written directly to
//      Vt[bh][d][2048] (natural key order, packed 8B stores)
//   3. attn: S^T operand-swap trick -- S^T C/D registers ARE the B-operand of
//      16x16x16 MFMA, so P feeds PV straight from registers (no LDS P
//      round-trip, no sigma). 128q tile/block, 1024 blocks, 16 KB LDS.
//   4. gemm_out: out = O @ wo.T (fp32)
// ---------------------------------------------------------------------------

typedef __attribute__((ext_vector_type(8))) short bf16x8;
typedef __attribute__((ext_vector_type(4))) short bf16x4;
typedef __attribute__((ext_vector_type(4))) float f32x4;
typedef unsigned short us;

#define LOG2E 1.4426950408889634f

#define GL2LDS16(g, l)                                                          \
  __builtin_amdgcn_global_load_lds(                                             \
      (const __attribute__((address_space(1))) unsigned int*)(g),               \
      (__attribute__((address_space(3))) unsigned int*)(l), 16, 0, 0)

__device__ inline us f2bf(float f) {
  union { float f; unsigned int u; } v; v.f = f;
  unsigned int u = v.u;
  u += 0x7FFFu + ((u >> 16) & 1u);
  return (us)(u >> 16);
}

// ---------------------------- fused casts ----------------------------------
__global__ void cast_all(const float* __restrict__ x,
                         const float* __restrict__ w0, const float* __restrict__ w1,
                         const float* __restrict__ w2, const float* __restrict__ w3,
                         us* __restrict__ xb, us* __restrict__ wbuf) {
  int i = (blockIdx.x * blockDim.x + threadIdx.x) * 8;
  const float* src;
  us* dst;
  float sc = 1.0f;
  if (i < (8 << 20)) {
    src = x + i; dst = xb + i;
  } else {
    int j = i - (8 << 20);
    int seg = j >> 20;
    int off = j & ((1 << 20) - 1);
    const float* w = (seg == 0) ? w0 : (seg == 1) ? w1 : (seg == 2) ? w2 : w3;
    if (seg == 0) sc = 0.125f * LOG2E;
    src = w + off; dst = wbuf + j;
  }
  float4 a = *reinterpret_cast<const float4*>(src);
  float4 b = *reinterpret_cast<const float4*>(src + 4);
  union { us u[8]; uint4 v; } o;
  o.u[0] = f2bf(a.x * sc); o.u[1] = f2bf(a.y * sc);
  o.u[2] = f2bf(a.z * sc); o.u[3] = f2bf(a.w * sc);
  o.u[4] = f2bf(b.x * sc); o.u[5] = f2bf(b.y * sc);
  o.u[6] = f2bf(b.z * sc); o.u[7] = f2bf(b.w * sc);
  *reinterpret_cast<uint4*>(dst) = o.v;
}

// -------------------- QKV GEMM (B^T), BK=64, fused V-transpose -------------
__global__ __launch_bounds__(256, 2) void gemm_qkv(
    const us* __restrict__ A, const us* __restrict__ Bw,
    us* __restrict__ QKV, us* __restrict__ Vt) {
  const int K = 1024, N = 3072;
  __shared__ __align__(16) us Al[128 * 64];
  __shared__ __align__(16) us Bl[128 * 64];
  const int tid = threadIdx.x;
  const int lane = tid & 63;
  const int w = tid >> 6;
  const int quad = lane >> 4;
  const int l16 = lane & 15;
  const int m0 = blockIdx.y * 128;
  const int n0 = blockIdx.x * 128;
  const int wm = w >> 1, wn = w & 1;
  const int srow_base = w * 8 + (lane >> 3);
  const int sunit = lane & 7;
  f32x4 acc[4][4] = {};

  for (int k0 = 0; k0 < K; k0 += 64) {
    __syncthreads();
#pragma unroll
    for (int it = 0; it < 4; ++it) {
      int row = it * 32 + srow_base;
      int gu = sunit ^ (row & 7);
      int base = __builtin_amdgcn_readfirstlane((it * 256 + w * 64) * 8);
      GL2LDS16(A + (size_t)(m0 + row) * K + k0 + gu * 8, &Al[base]);
      GL2LDS16(Bw + (size_t)(n0 + row) * K + k0 + gu * 8, &Bl[base]);
    }
    __syncthreads();
#pragma unroll
    for (int kk = 0; kk < 2; ++kk) {
      bf16x8 af[4], bfr[4];
#pragma unroll
      for (int mi = 0; mi < 4; ++mi) {
        int row = wm * 64 + mi * 16 + l16;
        af[mi] = *reinterpret_cast<const bf16x8*>(
            &Al[row * 64 + (((kk * 4 + quad) ^ (row & 7)) * 8)]);
      }
#pragma unroll
      for (int ni = 0; ni < 4; ++ni) {
        int row = wn * 64 + ni * 16 + l16;
        bfr[ni] = *reinterpret_cast<const bf16x8*>(
            &Bl[row * 64 + (((kk * 4 + quad) ^ (row & 7)) * 8)]);
      }
#pragma unroll
      for (int mi = 0; mi < 4; ++mi)
#pragma unroll
        for (int ni = 0; ni < 4; ++ni)
          acc[mi][ni] = __builtin_amdgcn_mfma_f32_16x16x32_bf16(af[mi], bfr[ni], acc[mi][ni], 0, 0, 0);
    }
  }

  if (n0 < 2048) {
#pragma unroll
    for (int mi = 0; mi < 4; ++mi)
#pragma unroll
      for (int ni = 0; ni < 4; ++ni)
#pragma unroll
        for (int r = 0; r < 4; ++r) {
          int row = m0 + wm * 64 + mi * 16 + quad * 4 + r;
          int col = n0 + wn * 64 + ni * 16 + l16;
          QKV[(size_t)row * N + col] = f2bf(acc[mi][ni][r]);
        }
  } else {
    // V epilogue: natural key order, 4 consecutive keys -> one 8B store
    const int b = m0 >> 11;
    const int kt = ((m0 & 2047) >> 6) + wm;
#pragma unroll
    for (int mi = 0; mi < 4; ++mi)
#pragma unroll
      for (int ni = 0; ni < 4; ++ni) {
        int col = n0 + wn * 64 + ni * 16 + l16;
        int h = (col - 2048) >> 6;
        int d = col & 63;
        int j0 = mi * 16 + quad * 4;
        union { us u[4]; uint2 v; } o4;
#pragma unroll
        for (int r = 0; r < 4; ++r) o4.u[r] = f2bf(acc[mi][ni][r]);
        *reinterpret_cast<uint2*>(
            &Vt[((size_t)((b * 16 + h) * 64 + d)) * 2048 + kt * 64 + j0]) = o4.v;
      }
  }
}

// ------------------------- out-proj GEMM (B^T), BK=64 ----------------------
__global__ __launch_bounds__(256, 2) void gemm_out(
    const us* __restrict__ A, const us* __restrict__ Bw,
    float* __restrict__ Cv, int M, int N, int K) {
  __shared__ __align__(16) us Al[128 * 64];
  __shared__ __align__(16) us Bl[128 * 64];
  const int tid = threadIdx.x;
  const int lane = tid & 63;
  const int w = tid >> 6;
  const int quad = lane >> 4;
  const int l16 = lane & 15;
  const int m0 = blockIdx.y * 128;
  const int n0 = blockIdx.x * 128;
  const int wm = w >> 1, wn = w & 1;
  const int srow_base = w * 8 + (lane >> 3);
  const int sunit = lane & 7;
  f32x4 acc[4][4] = {};

  for (int k0 = 0; k0 < K; k0 += 64) {
    __syncthreads();
#pragma unroll
    for (int it = 0; it < 4; ++it) {
      int row = it * 32 + srow_base;
      int gu = sunit ^ (row & 7);
      int base = __builtin_amdgcn_readfirstlane((it * 256 + w * 64) * 8);
      GL2LDS16(A + (size_t)(m0 + row) * K + k0 + gu * 8, &Al[base]);
      GL2LDS16(Bw + (size_t)(n0 + row) * K + k0 + gu * 8, &Bl[base]);
    }
    __syncthreads();
#pragma unroll
    for (int kk = 0; kk < 2; ++kk) {
      bf16x8 af[4], bfr[4];
#pragma unroll
      for (int mi = 0; mi < 4; ++mi) {
        int row = wm * 64 + mi * 16 + l16;
        af[mi] = *reinterpret_cast<const bf16x8*>(
            &Al[row * 64 + (((kk * 4 + quad) ^ (row & 7)) * 8)]);
      }
#pragma unroll
      for (int ni = 0; ni < 4; ++ni) {
        int row = wn * 64 + ni * 16 + l16;
        bfr[ni] = *reinterpret_cast<const bf16x8*>(
            &Bl[row * 64 + (((kk * 4 + quad) ^ (row & 7)) * 8)]);
      }
#pragma unroll
      for (int mi = 0; mi < 4; ++mi)
#pragma unroll
        for (int ni = 0; ni < 4; ++ni)
          acc[mi][ni] = __builtin_amdgcn_mfma_f32_16x16x32_bf16(af[mi], bfr[ni], acc[mi][ni], 0, 0, 0);
    }
  }

#pragma unroll
  for (int mi = 0; mi < 4; ++mi)
#pragma unroll
    for (int ni = 0; ni < 4; ++ni)
#pragma unroll
      for (int r = 0; r < 4; ++r) {
        int row = m0 + wm * 64 + mi * 16 + quad * 4 + r;
        int col = n0 + wn * 64 + ni * 16 + l16;
        Cv[(size_t)row * N + col] = acc[mi][ni][r];
      }
}

// ---------------------------- flash attention ------------------------------
// One 128q tile per block; 1024 blocks; 512 threads = 8 waves, wave w owns
// queries qrow..qrow+15 (qrow = q0 + w*16). Operand-swap: S^T = mfma(K, Q);
// S^T C/D regs (row=key quad*4+r, col=query l16) are the B-operand layout of
// v_mfma_f32_16x16x16_bf16, so P^T goes register->PV directly. O^T comes out
// with col=query, row=d. lsum via ones-MFMA (all C rows = per-query sum).
__global__ __launch_bounds__(512, 6) void attn(
    const us* __restrict__ QKV, const us* __restrict__ Vt,
    us* __restrict__ O) {
  __shared__ __align__(16) us Kl[64 * 64];
  __shared__ __align__(16) us Vl[64 * 64];
  const int bid = blockIdx.x;
  const int g = bid >> 6;
  const int qt = (g < 4) ? (15 - g) : (g < 8) ? (g - 4) : (g < 12) ? (19 - g) : (g - 8);
  const int bh = bid & 63;
  const int b = bh >> 4, h = bh & 15;
  const int q0 = qt * 128;
  const int tid = threadIdx.x, lane = tid & 63, w = tid >> 6;   // w in [0,8)
  const int quad = lane >> 4, l16 = lane & 15;
  const size_t rowbase = (size_t)b * 2048;
  const int qcol = h * 64;
  const int kcol = 1024 + h * 64;
  const int qrow = q0 + w * 16;            // this wave's strip
  const int nT = 2 * qt + 2;

  const bf16x4 ones4 = {(short)0x3F80, (short)0x3F80, (short)0x3F80, (short)0x3F80};

  // Q fragment: B-operand of S^T MFMA — lane l16 = query, d = quad*8+j.
  bf16x8 qf[2];
#pragma unroll
  for (int dc = 0; dc < 2; ++dc)
    qf[dc] = *reinterpret_cast<const bf16x8*>(
        &QKV[(rowbase + qrow + l16) * 3072 + qcol + dc * 32 + quad * 8]);

  f32x4 oacc[4] = {};                      // O^T: oacc[dt][r] = O[q=l16][dt*16+quad*4+r]
  f32x4 lacc = {};                         // per-query softmax sum (all r equal)

  const int rr = tid >> 3;                 // staged row 0..63
  const int gu = (tid & 7) ^ (rr & 7);     // source XOR swizzle
  const int sbase = __builtin_amdgcn_readfirstlane(w * 512);
  const int qv = qrow + l16;               // this lane's query index

  for (int kt = 0; kt < nT; ++kt) {
    __syncthreads();
    GL2LDS16(QKV + (rowbase + kt * 64 + rr) * 3072 + kcol + gu * 8, &Kl[sbase]);
    GL2LDS16(Vt + ((size_t)((b * 16 + h) * 64 + rr)) * 2048 + kt * 64 + gu * 8,
             &Vl[sbase]);
    __syncthreads();

    const int kdiff = qrow + 15 - kt * 64;
    if (kdiff < 0) continue;               // strip above diagonal
    const int tmax = (kdiff >= 48) ? 4 : ((kdiff >> 4) + 1);
    const bool do_mask = (kt * 64 + 63) > qrow;

    // S^T = K Q^T : s[t] holds keys t*16 + quad*4 + r, query l16
    f32x4 s[4];
#pragma unroll
    for (int t = 0; t < 4; ++t) {
      if (t < tmax) {
        s[t] = f32x4{0.f, 0.f, 0.f, 0.f};
        int krow = t * 16 + l16;
#pragma unroll
        for (int dc = 0; dc < 2; ++dc) {
          bf16x8 kf = *reinterpret_cast<const bf16x8*>(
              &Kl[krow * 64 + (((dc * 4 + quad) ^ (l16 & 7)) * 8)]);
          s[t] = __builtin_amdgcn_mfma_f32_16x16x32_bf16(kf, qf[dc], s[t], 0, 0, 0);
        }
      }
    }

    // p = exp2(s), causal mask; pack P^T into 16x16x16 B fragments; PV + lsum
#pragma unroll
    for (int t = 0; t < 4; ++t) {
      if (t < tmax) {
        float p[4];
        if (do_mask) {
#pragma unroll
          for (int r = 0; r < 4; ++r) {
            float e = __builtin_amdgcn_exp2f(s[t][r]);
            int kg = kt * 64 + t * 16 + quad * 4 + r;
            p[r] = (kg <= qv) ? e : 0.f;
          }
        } else {
#pragma unroll
          for (int r = 0; r < 4; ++r)
            p[r] = __builtin_amdgcn_exp2f(s[t][r]);
        }
        union { uint2 v; bf16x4 s4; } pt;
        pt.v.x = __builtin_amdgcn_perm(__float_as_uint(p[1]), __float_as_uint(p[0]), 0x07060302u);
        pt.v.y = __builtin_amdgcn_perm(__float_as_uint(p[3]), __float_as_uint(p[2]), 0x07060302u);
        lacc = __builtin_amdgcn_mfma_f32_16x16x16bf16_1k(ones4, pt.s4, lacc, 0, 0, 0);
#pragma unroll
        for (int dt = 0; dt < 4; ++dt) {
          int vrow = dt * 16 + l16;        // d row
          bf16x4 vf = *reinterpret_cast<const bf16x4*>(
              &Vl[vrow * 64 + (((t * 2 + (quad >> 1)) ^ (l16 & 7)) * 8) + (quad & 1) * 4]);
          oacc[dt] = __builtin_amdgcn_mfma_f32_16x16x16bf16_1k(vf, pt.s4, oacc[dt], 0, 0, 0);
        }
      }
    }
  }

  // epilogue: O[q=qrow+l16][qcol + dt*16 + quad*4 + r], 8B packed stores
  const float inv = 1.0f / lacc[0];
#pragma unroll
  for (int dt = 0; dt < 4; ++dt) {
    union { us u[4]; uint2 v; } o4;
#pragma unroll
    for (int r = 0; r < 4; ++r) o4.u[r] = f2bf(oacc[dt][r] * inv);
    *reinterpret_cast<uint2*>(
        &O[(rowbase + qrow + l16) * 1024 + qcol + dt * 16 + quad * 4]) = o4.v;
  }
}

// ------------------------------- launcher ----------------------------------
extern "C" void kernel_launch(void* const* d_in, const int* in_sizes, int n_in,
                              void* d_out, int out_size, void* d_ws, size_t ws_size,
                              hipStream_t stream) {
  const float* x = (const float*)d_in[0];
  const float* wq = (const float*)d_in[1];
  const float* wk = (const float*)d_in[2];
  const float* wv = (const float*)d_in[3];
  const float* wo = (const float*)d_in[4];

  const int BT = 8192, E = 1024;
  const size_t NX = (size_t)BT * E;
  const size_t NW = (size_t)E * E;

  us* xb = (us*)d_ws;                 // [8192][1024]; later reused as O
  us* wbuf = xb + NX;                 // wq|wk|wv|wo bf16
  us* QKV = wbuf + 4 * NW;            // [8192][3072] (V cols unused)
  us* VtB = QKV + (size_t)BT * 3 * E; // [64 bh][64 d][2048]
  us* Ob = xb;

  cast_all<<<(int)((NX + 4 * NW) / 8 / 256), 256, 0, stream>>>(x, wq, wk, wv, wo, xb, wbuf);

  gemm_qkv<<<dim3(24, 64), 256, 0, stream>>>(xb, wbuf, QKV, VtB);
  attn<<<1024, 512, 0, stream>>>(QKV, VtB, Ob);
  gemm_out<<<dim3(8, 64), 256, 0, stream>>>(Ob, wbuf + 3 * NW, (float*)d_out, BT, E, E);
}

// Round 11
// 224.302 us; speedup vs baseline: 1.8453x; 1.0589x over previous
//
#include <hip/hip_runtime.h>
#include <stdint.h>

// ---------------------------------------------------------------------------
// Causal self-attention, MI355X bf16-MFMA, round 11.
//   1. cast_all: x -> bf16, wq|wk|wv|wo -> bf16 (wq pre-scaled by 1/8*log2e)
//   2. gemm_qkv (BK=64, XOR-swizzled LDS): Q,K -> QKV; V written directly to
//      Vt[bh][d][2048] (natural key order, packed 8B stores)
//   3. attn: 128-KEY staging per barrier pair (2x64 halves), register-direct
//      P^T via operand swap (S^T = mfma(K,Q); C/D regs are 16x16x16 B-layout),
//      diagonal skip per half. 128q/block, 1024 blocks, 32 KB LDS.
//   4. gemm_out: out = O @ wo.T (fp32)
// ---------------------------------------------------------------------------

typedef __attribute__((ext_vector_type(8))) short bf16x8;
typedef __attribute__((ext_vector_type(4))) short bf16x4;
typedef __attribute__((ext_vector_type(4))) float f32x4;
typedef unsigned short us;

#define LOG2E 1.4426950408889634f

#define GL2LDS16(g, l)                                                          \
  __builtin_amdgcn_global_load_lds(                                             \
      (const __attribute__((address_space(1))) unsigned int*)(g),               \
      (__attribute__((address_space(3))) unsigned int*)(l), 16, 0, 0)

__device__ inline us f2bf(float f) {
  union { float f; unsigned int u; } v; v.f = f;
  unsigned int u = v.u;
  u += 0x7FFFu + ((u >> 16) & 1u);
  return (us)(u >> 16);
}

// ---------------------------- fused casts ----------------------------------
__global__ void cast_all(const float* __restrict__ x,
                         const float* __restrict__ w0, const float* __restrict__ w1,
                         const float* __restrict__ w2, const float* __restrict__ w3,
                         us* __restrict__ xb, us* __restrict__ wbuf) {
  int i = (blockIdx.x * blockDim.x + threadIdx.x) * 8;
  const float* src;
  us* dst;
  float sc = 1.0f;
  if (i < (8 << 20)) {
    src = x + i; dst = xb + i;
  } else {
    int j = i - (8 << 20);
    int seg = j >> 20;
    int off = j & ((1 << 20) - 1);
    const float* w = (seg == 0) ? w0 : (seg == 1) ? w1 : (seg == 2) ? w2 : w3;
    if (seg == 0) sc = 0.125f * LOG2E;
    src = w + off; dst = wbuf + j;
  }
  float4 a = *reinterpret_cast<const float4*>(src);
  float4 b = *reinterpret_cast<const float4*>(src + 4);
  union { us u[8]; uint4 v; } o;
  o.u[0] = f2bf(a.x * sc); o.u[1] = f2bf(a.y * sc);
  o.u[2] = f2bf(a.z * sc); o.u[3] = f2bf(a.w * sc);
  o.u[4] = f2bf(b.x * sc); o.u[5] = f2bf(b.y * sc);
  o.u[6] = f2bf(b.z * sc); o.u[7] = f2bf(b.w * sc);
  *reinterpret_cast<uint4*>(dst) = o.v;
}

// -------------------- QKV GEMM (B^T), BK=64, fused V-transpose -------------
__global__ __launch_bounds__(256, 2) void gemm_qkv(
    const us* __restrict__ A, const us* __restrict__ Bw,
    us* __restrict__ QKV, us* __restrict__ Vt) {
  const int K = 1024, N = 3072;
  __shared__ __align__(16) us Al[128 * 64];
  __shared__ __align__(16) us Bl[128 * 64];
  const int tid = threadIdx.x;
  const int lane = tid & 63;
  const int w = tid >> 6;
  const int quad = lane >> 4;
  const int l16 = lane & 15;
  const int m0 = blockIdx.y * 128;
  const int n0 = blockIdx.x * 128;
  const int wm = w >> 1, wn = w & 1;
  const int srow_base = w * 8 + (lane >> 3);
  const int sunit = lane & 7;
  f32x4 acc[4][4] = {};

  for (int k0 = 0; k0 < K; k0 += 64) {
    __syncthreads();
#pragma unroll
    for (int it = 0; it < 4; ++it) {
      int row = it * 32 + srow_base;
      int gu = sunit ^ (row & 7);
      int base = __builtin_amdgcn_readfirstlane((it * 256 + w * 64) * 8);
      GL2LDS16(A + (size_t)(m0 + row) * K + k0 + gu * 8, &Al[base]);
      GL2LDS16(Bw + (size_t)(n0 + row) * K + k0 + gu * 8, &Bl[base]);
    }
    __syncthreads();
#pragma unroll
    for (int kk = 0; kk < 2; ++kk) {
      bf16x8 af[4], bfr[4];
#pragma unroll
      for (int mi = 0; mi < 4; ++mi) {
        int row = wm * 64 + mi * 16 + l16;
        af[mi] = *reinterpret_cast<const bf16x8*>(
            &Al[row * 64 + (((kk * 4 + quad) ^ (row & 7)) * 8)]);
      }
#pragma unroll
      for (int ni = 0; ni < 4; ++ni) {
        int row = wn * 64 + ni * 16 + l16;
        bfr[ni] = *reinterpret_cast<const bf16x8*>(
            &Bl[row * 64 + (((kk * 4 + quad) ^ (row & 7)) * 8)]);
      }
#pragma unroll
      for (int mi = 0; mi < 4; ++mi)
#pragma unroll
        for (int ni = 0; ni < 4; ++ni)
          acc[mi][ni] = __builtin_amdgcn_mfma_f32_16x16x32_bf16(af[mi], bfr[ni], acc[mi][ni], 0, 0, 0);
    }
  }

  if (n0 < 2048) {
#pragma unroll
    for (int mi = 0; mi < 4; ++mi)
#pragma unroll
      for (int ni = 0; ni < 4; ++ni)
#pragma unroll
        for (int r = 0; r < 4; ++r) {
          int row = m0 + wm * 64 + mi * 16 + quad * 4 + r;
          int col = n0 + wn * 64 + ni * 16 + l16;
          QKV[(size_t)row * N + col] = f2bf(acc[mi][ni][r]);
        }
  } else {
    // V epilogue: natural key order, 4 consecutive keys -> one 8B store
    const int b = m0 >> 11;
    const int kt = ((m0 & 2047) >> 6) + wm;
#pragma unroll
    for (int mi = 0; mi < 4; ++mi)
#pragma unroll
      for (int ni = 0; ni < 4; ++ni) {
        int col = n0 + wn * 64 + ni * 16 + l16;
        int h = (col - 2048) >> 6;
        int d = col & 63;
        int j0 = mi * 16 + quad * 4;
        union { us u[4]; uint2 v; } o4;
#pragma unroll
        for (int r = 0; r < 4; ++r) o4.u[r] = f2bf(acc[mi][ni][r]);
        *reinterpret_cast<uint2*>(
            &Vt[((size_t)((b * 16 + h) * 64 + d)) * 2048 + kt * 64 + j0]) = o4.v;
      }
  }
}

// ------------------------- out-proj GEMM (B^T), BK=64 ----------------------
__global__ __launch_bounds__(256, 2) void gemm_out(
    const us* __restrict__ A, const us* __restrict__ Bw,
    float* __restrict__ Cv, int M, int N, int K) {
  __shared__ __align__(16) us Al[128 * 64];
  __shared__ __align__(16) us Bl[128 * 64];
  const int tid = threadIdx.x;
  const int lane = tid & 63;
  const int w = tid >> 6;
  const int quad = lane >> 4;
  const int l16 = lane & 15;
  const int m0 = blockIdx.y * 128;
  const int n0 = blockIdx.x * 128;
  const int wm = w >> 1, wn = w & 1;
  const int srow_base = w * 8 + (lane >> 3);
  const int sunit = lane & 7;
  f32x4 acc[4][4] = {};

  for (int k0 = 0; k0 < K; k0 += 64) {
    __syncthreads();
#pragma unroll
    for (int it = 0; it < 4; ++it) {
      int row = it * 32 + srow_base;
      int gu = sunit ^ (row & 7);
      int base = __builtin_amdgcn_readfirstlane((it * 256 + w * 64) * 8);
      GL2LDS16(A + (size_t)(m0 + row) * K + k0 + gu * 8, &Al[base]);
      GL2LDS16(Bw + (size_t)(n0 + row) * K + k0 + gu * 8, &Bl[base]);
    }
    __syncthreads();
#pragma unroll
    for (int kk = 0; kk < 2; ++kk) {
      bf16x8 af[4], bfr[4];
#pragma unroll
      for (int mi = 0; mi < 4; ++mi) {
        int row = wm * 64 + mi * 16 + l16;
        af[mi] = *reinterpret_cast<const bf16x8*>(
            &Al[row * 64 + (((kk * 4 + quad) ^ (row & 7)) * 8)]);
      }
#pragma unroll
      for (int ni = 0; ni < 4; ++ni) {
        int row = wn * 64 + ni * 16 + l16;
        bfr[ni] = *reinterpret_cast<const bf16x8*>(
            &Bl[row * 64 + (((kk * 4 + quad) ^ (row & 7)) * 8)]);
      }
#pragma unroll
      for (int mi = 0; mi < 4; ++mi)
#pragma unroll
        for (int ni = 0; ni < 4; ++ni)
          acc[mi][ni] = __builtin_amdgcn_mfma_f32_16x16x32_bf16(af[mi], bfr[ni], acc[mi][ni], 0, 0, 0);
    }
  }

#pragma unroll
  for (int mi = 0; mi < 4; ++mi)
#pragma unroll
    for (int ni = 0; ni < 4; ++ni)
#pragma unroll
      for (int r = 0; r < 4; ++r) {
        int row = m0 + wm * 64 + mi * 16 + quad * 4 + r;
        int col = n0 + wn * 64 + ni * 16 + l16;
        Cv[(size_t)row * N + col] = acc[mi][ni][r];
      }
}

// ---------------------------- flash attention ------------------------------
// One 128q tile per block; 1024 blocks; 512 threads = 8 waves, wave w owns
// queries qrow..qrow+15. 128 keys staged per barrier pair (two 64-key halves
// processed back-to-back). Operand-swap: S^T = mfma(K, Q); S^T C/D regs are
// the B-operand layout of v_mfma_f32_16x16x16_bf16 -> register-direct PV.
// nT64 = 2*qt+2 is even, so nT128 = qt+1 covers exactly.
__global__ __launch_bounds__(512, 6) void attn(
    const us* __restrict__ QKV, const us* __restrict__ Vt,
    us* __restrict__ O) {
  __shared__ __align__(16) us Kl[2][64 * 64];
  __shared__ __align__(16) us Vl[2][64 * 64];
  const int bid = blockIdx.x;
  const int g = bid >> 6;
  const int qt = (g < 4) ? (15 - g) : (g < 8) ? (g - 4) : (g < 12) ? (19 - g) : (g - 8);
  const int bh = bid & 63;
  const int b = bh >> 4, h = bh & 15;
  const int q0 = qt * 128;
  const int tid = threadIdx.x, lane = tid & 63, w = tid >> 6;   // w in [0,8)
  const int quad = lane >> 4, l16 = lane & 15;
  const size_t rowbase = (size_t)b * 2048;
  const int qcol = h * 64;
  const int kcol = 1024 + h * 64;
  const int qrow = q0 + w * 16;            // this wave's strip
  const int nT = qt + 1;                   // 128-key iterations

  const bf16x4 ones4 = {(short)0x3F80, (short)0x3F80, (short)0x3F80, (short)0x3F80};

  // Q fragment: B-operand of S^T MFMA — lane l16 = query, d = quad*8+j.
  bf16x8 qf[2];
#pragma unroll
  for (int dc = 0; dc < 2; ++dc)
    qf[dc] = *reinterpret_cast<const bf16x8*>(
        &QKV[(rowbase + qrow + l16) * 3072 + qcol + dc * 32 + quad * 8]);

  f32x4 oacc[4] = {};                      // O^T: oacc[dt][r] = O[q=l16][dt*16+quad*4+r]
  f32x4 lacc = {};                         // per-query softmax sum

  const int rr = tid >> 3;                 // staged row 0..63
  const int gu = (tid & 7) ^ (rr & 7);     // source XOR swizzle
  const int sbase = __builtin_amdgcn_readfirstlane(w * 512);
  const int qv = qrow + l16;               // this lane's query index

  for (int kt = 0; kt < nT; ++kt) {
    __syncthreads();
#pragma unroll
    for (int hf = 0; hf < 2; ++hf) {
      int kt64 = kt * 2 + hf;
      GL2LDS16(QKV + (rowbase + kt64 * 64 + rr) * 3072 + kcol + gu * 8,
               &Kl[hf][sbase]);
      GL2LDS16(Vt + ((size_t)((b * 16 + h) * 64 + rr)) * 2048 + kt64 * 64 + gu * 8,
               &Vl[hf][sbase]);
    }
    __syncthreads();

#pragma unroll
    for (int hf = 0; hf < 2; ++hf) {
      const int kt64 = kt * 2 + hf;
      const int kdiff = qrow + 15 - kt64 * 64;
      if (kdiff < 0) continue;             // this half fully above diagonal
      const int tmax = (kdiff >= 48) ? 4 : ((kdiff >> 4) + 1);
      const bool do_mask = (kt64 * 64 + 63) > qrow;
      const us* Klh = &Kl[hf][0];
      const us* Vlh = &Vl[hf][0];

      // S^T = K Q^T : s[t] holds keys t*16 + quad*4 + r, query l16
      f32x4 s[4];
#pragma unroll
      for (int t = 0; t < 4; ++t) {
        if (t < tmax) {
          s[t] = f32x4{0.f, 0.f, 0.f, 0.f};
          int krow = t * 16 + l16;
#pragma unroll
          for (int dc = 0; dc < 2; ++dc) {
            bf16x8 kf = *reinterpret_cast<const bf16x8*>(
                &Klh[krow * 64 + (((dc * 4 + quad) ^ (l16 & 7)) * 8)]);
            s[t] = __builtin_amdgcn_mfma_f32_16x16x32_bf16(kf, qf[dc], s[t], 0, 0, 0);
          }
        }
      }

      // p = exp2(s) + mask; P^T register-direct into 16x16x16 B fragments
#pragma unroll
      for (int t = 0; t < 4; ++t) {
        if (t < tmax) {
          float p[4];
          if (do_mask) {
#pragma unroll
            for (int r = 0; r < 4; ++r) {
              float e = __builtin_amdgcn_exp2f(s[t][r]);
              int kg = kt64 * 64 + t * 16 + quad * 4 + r;
              p[r] = (kg <= qv) ? e : 0.f;
            }
          } else {
#pragma unroll
            for (int r = 0; r < 4; ++r)
              p[r] = __builtin_amdgcn_exp2f(s[t][r]);
          }
          union { uint2 v; bf16x4 s4; } pt;
          pt.v.x = __builtin_amdgcn_perm(__float_as_uint(p[1]), __float_as_uint(p[0]), 0x07060302u);
          pt.v.y = __builtin_amdgcn_perm(__float_as_uint(p[3]), __float_as_uint(p[2]), 0x07060302u);
          lacc = __builtin_amdgcn_mfma_f32_16x16x16bf16_1k(ones4, pt.s4, lacc, 0, 0, 0);
#pragma unroll
          for (int dt = 0; dt < 4; ++dt) {
            int vrow = dt * 16 + l16;      // d row
            bf16x4 vf = *reinterpret_cast<const bf16x4*>(
                &Vlh[vrow * 64 + (((t * 2 + (quad >> 1)) ^ (l16 & 7)) * 8) + (quad & 1) * 4]);
            oacc[dt] = __builtin_amdgcn_mfma_f32_16x16x16bf16_1k(vf, pt.s4, oacc[dt], 0, 0, 0);
          }
        }
      }
    }
  }

  // epilogue: O[q=qrow+l16][qcol + dt*16 + quad*4 + r], 8B packed stores
  const float inv = 1.0f / lacc[0];
#pragma unroll
  for (int dt = 0; dt < 4; ++dt) {
    union { us u[4]; uint2 v; } o4;
#pragma unroll
    for (int r = 0; r < 4; ++r) o4.u[r] = f2bf(oacc[dt][r] * inv);
    *reinterpret_cast<uint2*>(
        &O[(rowbase + qrow + l16) * 1024 + qcol + dt * 16 + quad * 4]) = o4.v;
  }
}

// ------------------------------- launcher ----------------------------------
extern "C" void kernel_launch(void* const* d_in, const int* in_sizes, int n_in,
                              void* d_out, int out_size, void* d_ws, size_t ws_size,
                              hipStream_t stream) {
  const float* x = (const float*)d_in[0];
  const float* wq = (const float*)d_in[1];
  const float* wk = (const float*)d_in[2];
  const float* wv = (const float*)d_in[3];
  const float* wo = (const float*)d_in[4];

  const int BT = 8192, E = 1024;
  const size_t NX = (size_t)BT * E;
  const size_t NW = (size_t)E * E;

  us* xb = (us*)d_ws;                 // [8192][1024]; later reused as O
  us* wbuf = xb + NX;                 // wq|wk|wv|wo bf16
  us* QKV = wbuf + 4 * NW;            // [8192][3072] (V cols unused)
  us* VtB = QKV + (size_t)BT * 3 * E; // [64 bh][64 d][2048]
  us* Ob = xb;

  cast_all<<<(int)((NX + 4 * NW) / 8 / 256), 256, 0, stream>>>(x, wq, wk, wv, wo, xb, wbuf);

  gemm_qkv<<<dim3(24, 64), 256, 0, stream>>>(xb, wbuf, QKV, VtB);
  attn<<<1024, 512, 0, stream>>>(QKV, VtB, Ob);
  gemm_out<<<dim3(8, 64), 256, 0, stream>>>(Ob, wbuf + 3 * NW, (float*)d_out, BT, E, E);
}